// Round 10
// baseline (191.069 us; speedup 1.0000x reference)
//
#include <hip/hip_runtime.h>
#include <hip/hip_bf16.h>

#define BATCH 16
#define CDIM  512
#define SEQ   1024
#define HEADS 8
#define DHEAD 64
#define N3    1536      // 3 * HEADS * DHEAD
// q pre-scale: dk^-0.5 * log2(e), so attn uses exp2 directly (softmax-invariant)
#define QSCALE 0.18033688011112042f

typedef unsigned short ushort_t;
typedef __attribute__((ext_vector_type(8))) short short8;   // 8 bf16 (4 VGPRs)
typedef __attribute__((ext_vector_type(4))) float f32x4;

// fp32 -> bf16 bits, round-to-nearest-even
__device__ __forceinline__ unsigned f2bf(float f) {
    unsigned u = __float_as_uint(f);
    u += 0x7fffu + ((u >> 16) & 1u);
    return u >> 16;
}
// 2^x via v_exp_f32 (quarter-rate transcendental; inputs are normal-range)
__device__ __forceinline__ float fast_exp2(float x) {
    float r;
    asm("v_exp_f32 %0, %1" : "=v"(r) : "v"(x));
    return r;
}
// pack trunc-bf16(lo), trunc-bf16(hi) -> one u32 via v_perm_b32 (1 VALU op)
__device__ __forceinline__ unsigned pack_bf16_trunc(float lo, float hi) {
    return __builtin_amdgcn_perm(__float_as_uint(hi), __float_as_uint(lo), 0x07060302u);
}
// async global->LDS, 16B/lane; per-lane ptr pre-offset by lane*16B so each
// wave covers 1 KB CONTIGUOUS global memory (one transaction, not 64).
__device__ __forceinline__ void async16(const void* g, void* l) {
    __builtin_amdgcn_global_load_lds(
        (const __attribute__((address_space(1))) unsigned int*)g,
        (__attribute__((address_space(3))) unsigned int*)l, 16, 0, 0);
}
// raw barrier (no vmcnt drain) fenced against compiler reordering
__device__ __forceinline__ void barrier_raw() {
    __builtin_amdgcn_sched_barrier(0);
    __builtin_amdgcn_s_barrier();
    __builtin_amdgcn_sched_barrier(0);
}
// counted vmcnt wait: leaves newest N loads in flight across the barrier (T4)
#define WAIT_VMCNT(n) asm volatile("s_waitcnt vmcnt(" #n ")" ::: "memory")

// ---------------------------------------------------------------------------
// Blocked fragment-order layout for GEMM staging (all staged operands):
//   element (m, k):  mt=m>>7, mr=m&127, m16=mr>>4, col=mr&15,
//                    it=k>>5, q=(k>>3)&3, j=k&7
//   off = ((mt*16+it)*8 + m16)*512 + (q*16+col)*8 + j
// One (mt,it,m16) chunk = 512 ushorts = 1 KB contiguous = one async16/wave.
// ---------------------------------------------------------------------------

// Kernel 0: transpose + bf16 + blockify, FUSED for all three operands.
//   z<16 -> x (batch z, C=1024); z==16 -> Wp (C=1536); z==17 -> Wo (C=512).
//   float4 global loads (1 KB/wave-instr); LDS [64][68] keeps 16B alignment.
//   Grid: (24, 8, 18); 256 threads.
__global__ __launch_bounds__(256) void blockify_kernel(
    const float* __restrict__ x, const float* __restrict__ Wp,
    const float* __restrict__ Wo,
    ushort_t* __restrict__ xtb, ushort_t* __restrict__ WpTb,
    ushort_t* __restrict__ WoTb)
{
    const int zz = blockIdx.z;
    const float* in;
    ushort_t* out;
    int C, zbat;
    if (zz < 16)       { if (blockIdx.x >= 16) return; in = x;  out = xtb;  C = 1024; zbat = zz; }
    else if (zz == 16) {                               in = Wp; out = WpTb; C = 1536; zbat = 0;  }
    else               { if (blockIdx.x >= 8)  return; in = Wo; out = WoTb; C = 512;  zbat = 0;  }

    __shared__ float t[64][68];
    const int k0 = blockIdx.y * 64, c0 = blockIdx.x * 64;
    const float* inb = in + (size_t)zbat * 512 * C;
    const int tid = threadIdx.x;
#pragma unroll
    for (int i = 0; i < 4; ++i) {
        int idx = tid + i * 256;           // 0..1023 float4 slots
        int r = idx >> 4, c4 = idx & 15;
        float4 f = *(const float4*)&inb[(size_t)(k0 + r) * C + c0 + c4 * 4];
        *(float4*)&t[r][c4 * 4] = f;
    }
    __syncthreads();
    const size_t mbase = (size_t)zbat * C + c0;
    const int ml = tid & 63;
#pragma unroll
    for (int i = 0; i < 2; ++i) {
        int oct = (tid >> 6) + i * 4;          // k-octet 0..7
        size_t m = mbase + ml;
        int mt = (int)(m >> 7), mr = (int)(m & 127);
        int m16 = mr >> 4, col = mr & 15;
        int k = k0 + oct * 8;
        int it = k >> 5, q = (k >> 3) & 3;
        uint4 pk;
        pk.x = f2bf(t[oct * 8 + 0][ml]) | (f2bf(t[oct * 8 + 1][ml]) << 16);
        pk.y = f2bf(t[oct * 8 + 2][ml]) | (f2bf(t[oct * 8 + 3][ml]) << 16);
        pk.z = f2bf(t[oct * 8 + 4][ml]) | (f2bf(t[oct * 8 + 5][ml]) << 16);
        pk.w = f2bf(t[oct * 8 + 6][ml]) | (f2bf(t[oct * 8 + 7][ml]) << 16);
        size_t off = ((size_t)(mt * 16 + it) * 8 + m16) * 512 + (q * 16 + col) * 8;
        *(uint4*)&out[off] = pk;
    }
}

// ---------------------------------------------------------------------------
// Kernel 1: QKV GEMM (MFMA), BK=32, blocked contiguous staging, XCD swizzle.
//   v3: 4 waves x (64m x 64n), counted-vmcnt pipeline (T3+T4): prefetch
//   depth 2, raw barriers, vmcnt(4) keeps next tile's loads in flight.
//   v4: V written in pi-permuted row order so attn's PV A-fragments need
//   NO LDS round-trip.  Grid: (12, 128); 256 thr; 32 KB LDS.
// ---------------------------------------------------------------------------
__global__ __launch_bounds__(256) void qkv_gemm_kernel(
    const ushort_t* __restrict__ xtb, const ushort_t* __restrict__ WpTb,
    const float* __restrict__ bp,
    ushort_t* __restrict__ q_buf, ushort_t* __restrict__ kb,
    ushort_t* __restrict__ vb)
{
    __shared__ alignas(16) ushort_t Asub[2][8 * 512];   // 2 x 8 KB
    __shared__ alignas(16) ushort_t Bsub[2][8 * 512];   // 2 x 8 KB

    const int tid = threadIdx.x, w = tid >> 6, lane = tid & 63;
    const int quad = lane >> 4, col = lane & 15;
    const int wm = w >> 1, wn = w & 1;

    // XCD swizzle: all 12 n-tiles of one m-tile on one XCD
    const int lin = blockIdx.x + 12 * blockIdx.y;   // 0..1535
    const int xcd = lin & 7;
    const int rr  = lin >> 3;
    const int n0  = (rr % 12) * 128;
    const int m0  = ((rr / 12) * 8 + xcd) * 128;

    f32x4 acc[4][4];
#pragma unroll
    for (int i = 0; i < 4; ++i)
#pragma unroll
        for (int j = 0; j < 4; ++j) acc[i][j] = (f32x4){0.f, 0.f, 0.f, 0.f};

    const ushort_t* Ab = xtb  + (size_t)(m0 >> 7) * 65536 + (w * 2) * 512 + lane * 8;
    const ushort_t* Bb = WpTb + (size_t)(n0 >> 7) * 65536 + (w * 2) * 512 + lane * 8;

#define QKV_STAGE(buf, t)                                         \
    do {                                                          \
        async16(Ab + (t) * 4096,       &Asub[buf][(w * 2 + 0) * 512]); \
        async16(Ab + (t) * 4096 + 512, &Asub[buf][(w * 2 + 1) * 512]); \
        async16(Bb + (t) * 4096,       &Bsub[buf][(w * 2 + 0) * 512]); \
        async16(Bb + (t) * 4096 + 512, &Bsub[buf][(w * 2 + 1) * 512]); \
    } while (0)

    QKV_STAGE(0, 0);
    QKV_STAGE(1, 1);
    for (int it = 0; it < 16; ++it) {
        const int cur = it & 1;
        if (it < 15) { WAIT_VMCNT(4); } else { WAIT_VMCNT(0); }
        barrier_raw();                   // buf[cur] staged for all waves

        short8 af[4], bfr[4];
#pragma unroll
        for (int i = 0; i < 4; ++i) af[i]  = *(const short8*)&Asub[cur][(wm * 4 + i) * 512 + lane * 8];
#pragma unroll
        for (int j = 0; j < 4; ++j) bfr[j] = *(const short8*)&Bsub[cur][(wn * 4 + j) * 512 + lane * 8];
#pragma unroll
        for (int i = 0; i < 4; ++i)
#pragma unroll
            for (int j = 0; j < 4; ++j)
                acc[i][j] = __builtin_amdgcn_mfma_f32_16x16x32_bf16(af[i], bfr[j], acc[i][j], 0, 0, 0);

        if (it < 14) {
            barrier_raw();               // all waves done reading buf[cur]
            QKV_STAGE(cur, it + 2);
        }
    }
#undef QKV_STAGE

    // ---- epilogue: split q/k/v; q pre-scaled by QSCALE ----
    const int b = m0 >> 10, s0 = m0 & 1023;
    const size_t b8 = (size_t)b * HEADS;
#pragma unroll
    for (int j = 0; j < 4; ++j) {
        int nb = n0 + wn * 64 + j * 16;               // frag n base (wave-uniform)
        int h = nb / 192, rem = nb % 192;
        int type = rem >> 6, dbase = rem & 63;        // uniform per frag
        float bias = bp[nb + col];
        size_t bh = b8 + h;
        int d = dbase + col;
#pragma unroll
        for (int i = 0; i < 4; ++i) {
            int sb = s0 + wm * 64 + i * 16 + quad * 4;    // s for r=0
            f32x4 v = acc[i][j];
            if (type == 2) {
                // vb blocked + pi-permuted rows: slot tau for t=sb..sb+3 is
                // contiguous: tau&7 = ((sb>>4)&1)*4 + r, quad-slot = (sb>>2)&3
                unsigned lo = f2bf(v[0] + bias) | (f2bf(v[1] + bias) << 16);
                unsigned hi = f2bf(v[2] + bias) | (f2bf(v[3] + bias) << 16);
                uint2 pk; pk.x = lo; pk.y = hi;
                int itv = sb >> 6, sub = (d >> 4) * 2 + ((sb >> 5) & 1);
                size_t off = ((bh * 16 + itv) * 8 + sub) * 512
                           + (((sb >> 2) & 3) * 16 + (d & 15)) * 8
                           + ((sb >> 4) & 1) * 4;
                *(uint2*)&vb[off] = pk;
            } else if (type == 1) {
                // kb blocked: elem (bh,t,d): it=t>>6, sub=((t>>4)&3)*2+(d>>5)
#pragma unroll
                for (int r = 0; r < 4; ++r) {
                    int t = sb + r;
                    int itk = t >> 6, sub = ((t >> 4) & 3) * 2 + (d >> 5);
                    size_t off = ((bh * 16 + itk) * 8 + sub) * 512
                               + (((d >> 3) & 3) * 16 + (t & 15)) * 8 + (d & 7);
                    kb[off] = (ushort_t)f2bf(v[r] + bias);
                }
            } else {
#pragma unroll
                for (int r = 0; r < 4; ++r)
                    q_buf[(bh * SEQ + sb + r) * DHEAD + d] =
                        (ushort_t)f2bf((v[r] + bias) * QSCALE);
            }
        }
    }
}

// ---------------------------------------------------------------------------
// Kernel 2: MFMA flash attention; blocked contiguous K/V staging; dbuf;
//   unnormalized softmax via exp2 (q pre-scaled by log2e); S^T trick.
//   v4 (measured best, 50.0-52.3 us): ZERO P round-trip — V rows pi-permuted
//   in vb so each lane's S^T values ARE its PV A-fragment after exp2+pack.
//   2 waves x 4 q-groups; __syncthreads dbuf; 32 KB LDS -> 4 blocks/CU.
//   (R5 SW-pipeline and R6 4-wave variants both regressed; reverted.)
//   Grid: (bh=128, qtile=8); 128 threads.
// ---------------------------------------------------------------------------
__global__ __launch_bounds__(128) void attn_kernel(
    const ushort_t* __restrict__ q_buf, const ushort_t* __restrict__ kb,
    const ushort_t* __restrict__ vb, ushort_t* __restrict__ resb)
{
    __shared__ alignas(16) ushort_t Kf[2][8 * 512];   // ping-pong, 16 KB
    __shared__ alignas(16) ushort_t Vf[2][8 * 512];   // ping-pong, 16 KB

    const int tid  = threadIdx.x;
    const int w    = tid >> 6;            // 0..1
    const int lane = tid & 63;
    const int quad = lane >> 4;
    const int col  = lane & 15;

    const int bhid = blockIdx.x;          // 0..127
    const int b = bhid >> 3, h = bhid & 7;
    const int q0 = blockIdx.y * 128;
    const size_t bh = (size_t)b * HEADS + h;

    // Q B-frags for 4 groups (pre-scaled by QSCALE in qkv_gemm)
    // group g covers q rows q0 + w*64 + g*16 .. +15
    const ushort_t* qp = q_buf + ((bh * SEQ) + q0 + w * 64 + col) * DHEAD + quad * 8;
    short8 qf0[4], qf1[4];
#pragma unroll
    for (int g = 0; g < 4; ++g) {
        qf0[g] = *(const short8*)(qp + g * 16 * DHEAD);
        qf1[g] = *(const short8*)(qp + g * 16 * DHEAD + 32);
    }

    short8 ones;
#pragma unroll
    for (int i = 0; i < 8; ++i) ones[i] = (short)0x3F80;

    f32x4 O[4][4];
#pragma unroll
    for (int g = 0; g < 4; ++g)
#pragma unroll
        for (int i = 0; i < 4; ++i) O[g][i] = (f32x4){0.f, 0.f, 0.f, 0.f};
    f32x4 L[4];
#pragma unroll
    for (int g = 0; g < 4; ++g) L[g] = (f32x4){0.f, 0.f, 0.f, 0.f};

    // blocked contiguous staging pointers (wave w stages subs w*4+{0..3})
    const ushort_t* kaB = kb + (size_t)bh * 65536 + (w * 4) * 512 + lane * 8;
    const ushort_t* vaB = vb + (size_t)bh * 65536 + (w * 4) * 512 + lane * 8;

#define ATTN_STAGE(buf)                                            \
    do {                                                           \
        async16(kaB,        &Kf[buf][(w * 4 + 0) * 512]);          \
        async16(kaB + 512,  &Kf[buf][(w * 4 + 1) * 512]);          \
        async16(kaB + 1024, &Kf[buf][(w * 4 + 2) * 512]);          \
        async16(kaB + 1536, &Kf[buf][(w * 4 + 3) * 512]);          \
        async16(vaB,        &Vf[buf][(w * 4 + 0) * 512]);          \
        async16(vaB + 512,  &Vf[buf][(w * 4 + 1) * 512]);          \
        async16(vaB + 1024, &Vf[buf][(w * 4 + 2) * 512]);          \
        async16(vaB + 1536, &Vf[buf][(w * 4 + 3) * 512]);          \
        kaB += 4096;                                               \
        vaB += 4096;                                               \
    } while (0)

    ATTN_STAGE(0);

    for (int it = 0; it < 16; ++it) {
        const int cur = it & 1;
        const ushort_t* kc = Kf[cur];
        const ushort_t* vc = Vf[cur];
        __syncthreads();   // buf[cur] staged; prior readers of buf[cur^1] done
        if (it < 15) ATTN_STAGE(cur ^ 1);

        // ---- K frags to regs once; shared by all 4 groups ----
        short8 kf[8];
#pragma unroll
        for (int t16 = 0; t16 < 4; ++t16) {
            kf[2 * t16 + 0] = *(const short8*)&kc[(t16 * 2 + 0) * 512 + lane * 8];
            kf[2 * t16 + 1] = *(const short8*)&kc[(t16 * 2 + 1) * 512 + lane * 8];
        }

        // ---- per group: S^T = K Q^T; P fragments built IN REGISTERS ----
        // lane holds S^T[t=t16*16+quad*4+r][q=col]; under vb's pi-permutation
        // pf[0] = bf16(exp2(S[0][0..3]), exp2(S[1][0..3])), pf[1] = t16 2,3.
        short8 pf[4][2];
#pragma unroll
        for (int g = 0; g < 4; ++g) {
            f32x4 S[4];
            __builtin_amdgcn_s_setprio(1);
#pragma unroll
            for (int t16 = 0; t16 < 4; ++t16) {
                f32x4 a = (f32x4){0.f, 0.f, 0.f, 0.f};
                a = __builtin_amdgcn_mfma_f32_16x16x32_bf16(kf[2 * t16 + 0], qf0[g], a, 0, 0, 0);
                a = __builtin_amdgcn_mfma_f32_16x16x32_bf16(kf[2 * t16 + 1], qf1[g], a, 0, 0, 0);
                S[t16] = a;
            }
            __builtin_amdgcn_s_setprio(0);
            union { uint4 u; short8 s; } p0, p1;
            p0.u.x = pack_bf16_trunc(fast_exp2(S[0][0]), fast_exp2(S[0][1]));
            p0.u.y = pack_bf16_trunc(fast_exp2(S[0][2]), fast_exp2(S[0][3]));
            p0.u.z = pack_bf16_trunc(fast_exp2(S[1][0]), fast_exp2(S[1][1]));
            p0.u.w = pack_bf16_trunc(fast_exp2(S[1][2]), fast_exp2(S[1][3]));
            p1.u.x = pack_bf16_trunc(fast_exp2(S[2][0]), fast_exp2(S[2][1]));
            p1.u.y = pack_bf16_trunc(fast_exp2(S[2][2]), fast_exp2(S[2][3]));
            p1.u.z = pack_bf16_trunc(fast_exp2(S[3][0]), fast_exp2(S[3][1]));
            p1.u.w = pack_bf16_trunc(fast_exp2(S[3][2]), fast_exp2(S[3][3]));
            pf[g][0] = p0.s;
            pf[g][1] = p1.s;
        }

        // ---- O += P V ; V frags read once/d16, shared by 4 groups ----
#pragma unroll
        for (int d16 = 0; d16 < 4; ++d16) {
            const short8 v0 = *(const short8*)&vc[(d16 * 2 + 0) * 512 + lane * 8];
            const short8 v1 = *(const short8*)&vc[(d16 * 2 + 1) * 512 + lane * 8];
            __builtin_amdgcn_s_setprio(1);
#pragma unroll
            for (int g = 0; g < 4; ++g) {
                O[g][d16] = __builtin_amdgcn_mfma_f32_16x16x32_bf16(pf[g][0], v0, O[g][d16], 0, 0, 0);
                O[g][d16] = __builtin_amdgcn_mfma_f32_16x16x32_bf16(pf[g][1], v1, O[g][d16], 0, 0, 0);
            }
            __builtin_amdgcn_s_setprio(0);
        }
#pragma unroll
        for (int g = 0; g < 4; ++g) {
            L[g] = __builtin_amdgcn_mfma_f32_16x16x32_bf16(pf[g][0], ones, L[g], 0, 0, 0);
            L[g] = __builtin_amdgcn_mfma_f32_16x16x32_bf16(pf[g][1], ones, L[g], 0, 0, 0);
        }
    }
#undef ATTN_STAGE

    // ---- epilogue: O / L -> resb in out_gemm's blocked order ----
    const int mt = b * 8 + (q0 >> 7);
#pragma unroll
    for (int g = 0; g < 4; ++g) {
        const int m16 = w * 4 + g;
#pragma unroll
        for (int r = 0; r < 4; ++r) {
            float inv = 1.f / L[g][r];
            const int mcol = quad * 4 + r;
#pragma unroll
            for (int d16 = 0; d16 < 4; ++d16) {
                int itk = h * 2 + (d16 >> 1);
                int kq = (d16 & 1) * 2 + (col >> 3);
                size_t off = ((size_t)(mt * 16 + itk) * 8 + m16) * 512
                           + (kq * 16 + mcol) * 8 + (col & 7);
                resb[off] = (ushort_t)f2bf(O[g][d16][r] * inv);
            }
        }
    }
}

// ---------------------------------------------------------------------------
// Kernel 3: out GEMM (MFMA), BK=32, blocked staging, XCD swizzle.
//   v5: 64m x 128n tiles — grid (4, 256) = 1024 blocks = 4 blocks/CU
//   (was 512 = 2/CU: machine half-idle).  4 waves as 2m x 2n (wave 32m x
//   64n, acc[2][4]); 3 async16/wave/tile; WAIT_VMCNT(3); LDS 24 KB.
//   Coalesced LDS-transpose epilogue (4 n-rows x 64 contiguous s / instr).
// ---------------------------------------------------------------------------
__global__ __launch_bounds__(256) void out_gemm_kernel(
    const ushort_t* __restrict__ resb, const ushort_t* __restrict__ WoTb,
    const float* __restrict__ bo, const float* __restrict__ x,
    float* __restrict__ out)
{
    __shared__ alignas(16) ushort_t SMEM[(2 * 4 + 2 * 8) * 512];   // 24 KB
    ushort_t (*Asub)[4 * 512] = (ushort_t (*)[4 * 512])(SMEM);
    ushort_t (*Bsub)[8 * 512] = (ushort_t (*)[8 * 512])(SMEM + 2 * 4 * 512);
    float* tb = (float*)SMEM;            // epilogue overlay [32][68] fp32 (8.7 KB)

    const int tid = threadIdx.x, w = tid >> 6, lane = tid & 63;
    const int quad = lane >> 4, col = lane & 15;
    const int wm = w >> 1, wn = w & 1;

    const int lin = blockIdx.x + 4 * blockIdx.y;    // 0..1023
    const int xcd = lin & 7;
    const int rr  = lin >> 3;                       // 0..127
    const int n0  = (rr & 3) * 128;
    const int m0  = ((rr >> 2) * 8 + xcd) * 64;     // 64-row m-tiles

    f32x4 acc[2][4];
#pragma unroll
    for (int i = 0; i < 2; ++i)
#pragma unroll
        for (int j = 0; j < 4; ++j) acc[i][j] = (f32x4){0.f, 0.f, 0.f, 0.f};

    const int mt = m0 >> 7, mhalf = (m0 >> 6) & 1;
    const ushort_t* Ab = resb + (size_t)mt * 65536 + (size_t)(mhalf * 4 + w) * 512 + lane * 8;
    const ushort_t* Bb = WoTb + (size_t)(n0 >> 7) * 65536 + (w * 2) * 512 + lane * 8;

#define OUT_STAGE(buf, t)                                              \
    do {                                                               \
        async16(Ab + (t) * 4096,       &Asub[buf][w * 512]);           \
        async16(Bb + (t) * 4096,       &Bsub[buf][(w * 2 + 0) * 512]); \
        async16(Bb + (t) * 4096 + 512, &Bsub[buf][(w * 2 + 1) * 512]); \
    } while (0)

    OUT_STAGE(0, 0);
    OUT_STAGE(1, 1);
    for (int it = 0; it < 16; ++it) {
        const int cur = it & 1;
        if (it < 15) { WAIT_VMCNT(3); } else { WAIT_VMCNT(0); }
        barrier_raw();

        short8 af[2], bfr[4];
#pragma unroll
        for (int i = 0; i < 2; ++i) af[i]  = *(const short8*)&Asub[cur][(wm * 2 + i) * 512 + lane * 8];
#pragma unroll
        for (int j = 0; j < 4; ++j) bfr[j] = *(const short8*)&Bsub[cur][(wn * 4 + j) * 512 + lane * 8];
#pragma unroll
        for (int i = 0; i < 2; ++i)
#pragma unroll
            for (int j = 0; j < 4; ++j)
                acc[i][j] = __builtin_amdgcn_mfma_f32_16x16x32_bf16(af[i], bfr[j], acc[i][j], 0, 0, 0);

        if (it < 14) {
            barrier_raw();
            OUT_STAGE(cur, it + 2);
        }
    }
#undef OUT_STAGE

    // ---- coalesced epilogue via LDS transpose ----
    // Per j-pass: waves stage acc[:,j] (32 n x 64 s fp32) into tb, then each
    // instruction streams 4 n-rows x 64 contiguous s (4 x 256 B segments).
    const int b = m0 >> 10, s0 = m0 & 1023;
#pragma unroll
    for (int j = 0; j < 4; ++j) {
        __syncthreads();   // previous pass readers / main-loop readers done
#pragma unroll
        for (int i = 0; i < 2; ++i) {
            f32x4 v = acc[i][j];
            float* dst = &tb[(wn * 16 + col) * 68 + wm * 32 + i * 16 + quad * 4];
            dst[0] = v[0]; dst[1] = v[1]; dst[2] = v[2]; dst[3] = v[3];
        }
        __syncthreads();   // tb fully staged
#pragma unroll
        for (int p = 0; p < 2; ++p) {
            int nl = w * 8 + p * 4 + (lane >> 4);          // 0..31
            int n = n0 + j * 16 + (nl & 15) + (nl >> 4) * 64;
            int scol = (lane & 15) * 4;
            float4 t4 = *(const float4*)&tb[nl * 68 + scol];
            size_t o = ((size_t)b * CDIM + n) * SEQ + s0 + scol;
            float4 xr = *(const float4*)&x[o];
            float bias = bo[n];
            float4 ov;
            ov.x = t4.x + bias + xr.x;
            ov.y = t4.y + bias + xr.y;
            ov.z = t4.z + bias + xr.z;
            ov.w = t4.w + bias + xr.w;
            *(float4*)&out[o] = ov;
        }
    }
}

// ---------------------------------------------------------------------------
extern "C" void kernel_launch(void* const* d_in, const int* in_sizes, int n_in,
                              void* d_out, int out_size, void* d_ws, size_t ws_size,
                              hipStream_t stream) {
    const float* x  = (const float*)d_in[0];   // (16, 512, 32, 32) fp32
    const float* Wp = (const float*)d_in[1];   // (512, 1536) fp32
    const float* bp = (const float*)d_in[2];   // (1536,) fp32
    const float* Wo = (const float*)d_in[3];   // (512, 512) fp32
    const float* bo = (const float*)d_in[4];   // (512,) fp32
    float* out = (float*)d_out;                // (16, 512, 32, 32) fp32

    // ws layout (ushort units), ~86 MB
    ushort_t* xtb   = (ushort_t*)d_ws;               // blocked [mt][it][sub][lane][8]
    ushort_t* WpTb  = xtb   + (size_t)8388608;
    ushort_t* WoTb  = WpTb  + (size_t)786432;
    ushort_t* q_buf = WoTb  + (size_t)262144;        // row-major [bh][s][d]
    ushort_t* kb    = q_buf + (size_t)8388608;       // attn-blocked
    ushort_t* vb    = kb    + (size_t)8388608;       // attn-blocked, pi-permuted rows
    ushort_t* resb  = vb    + (size_t)8388608;       // out_gemm-blocked

    blockify_kernel<<<dim3(24, 8, 18), 256, 0, stream>>>(x, Wp, Wo, xtb, WpTb, WoTb);
    qkv_gemm_kernel<<<dim3(12, 128), 256, 0, stream>>>(xtb, WpTb, bp, q_buf, kb, vb);
    attn_kernel<<<dim3(128, 8), 128, 0, stream>>>(q_buf, kb, vb, resb);
    out_gemm_kernel<<<dim3(4, 256), 256, 0, stream>>>(resb, WoTb, bo, x, out);
}

// Round 11
// 186.715 us; speedup vs baseline: 1.0233x; 1.0233x over previous
//
#include <hip/hip_runtime.h>
#include <hip/hip_bf16.h>

#define BATCH 16
#define CDIM  512
#define SEQ   1024
#define HEADS 8
#define DHEAD 64
#define N3    1536      // 3 * HEADS * DHEAD
// q pre-scale: dk^-0.5 * log2(e), so attn uses exp2 directly (softmax-invariant)
#define QSCALE 0.18033688011112042f

typedef unsigned short ushort_t;
typedef __attribute__((ext_vector_type(8))) short short8;   // 8 bf16 (4 VGPRs)
typedef __attribute__((ext_vector_type(4))) float f32x4;

// fp32 -> bf16 bits, round-to-nearest-even
__device__ __forceinline__ unsigned f2bf(float f) {
    unsigned u = __float_as_uint(f);
    u += 0x7fffu + ((u >> 16) & 1u);
    return u >> 16;
}
// 2^x via v_exp_f32 (quarter-rate transcendental; inputs are normal-range)
__device__ __forceinline__ float fast_exp2(float x) {
    float r;
    asm("v_exp_f32 %0, %1" : "=v"(r) : "v"(x));
    return r;
}
// pack trunc-bf16(lo), trunc-bf16(hi) -> one u32 via v_perm_b32 (1 VALU op)
__device__ __forceinline__ unsigned pack_bf16_trunc(float lo, float hi) {
    return __builtin_amdgcn_perm(__float_as_uint(hi), __float_as_uint(lo), 0x07060302u);
}
// async global->LDS, 16B/lane; per-lane ptr pre-offset by lane*16B so each
// wave covers 1 KB CONTIGUOUS global memory (one transaction, not 64).
__device__ __forceinline__ void async16(const void* g, void* l) {
    __builtin_amdgcn_global_load_lds(
        (const __attribute__((address_space(1))) unsigned int*)g,
        (__attribute__((address_space(3))) unsigned int*)l, 16, 0, 0);
}
// raw barrier (no vmcnt drain) fenced against compiler reordering
__device__ __forceinline__ void barrier_raw() {
    __builtin_amdgcn_sched_barrier(0);
    __builtin_amdgcn_s_barrier();
    __builtin_amdgcn_sched_barrier(0);
}
// counted vmcnt wait: leaves newest N loads in flight across the barrier (T4)
#define WAIT_VMCNT(n) asm volatile("s_waitcnt vmcnt(" #n ")" ::: "memory")

// ---------------------------------------------------------------------------
// Blocked fragment-order layout for GEMM staging (all staged operands):
//   element (m, k):  mt=m>>7, mr=m&127, m16=mr>>4, col=mr&15,
//                    it=k>>5, q=(k>>3)&3, j=k&7
//   off = ((mt*16+it)*8 + m16)*512 + (q*16+col)*8 + j
// One (mt,it,m16) chunk = 512 ushorts = 1 KB contiguous = one async16/wave.
// ---------------------------------------------------------------------------

// Kernel 0: transpose + bf16 + blockify, FUSED for all three operands.
//   z<16 -> x (batch z, C=1024); z==16 -> Wp (C=1536); z==17 -> Wo (C=512).
//   float4 global loads (1 KB/wave-instr); LDS [64][68] keeps 16B alignment.
//   Grid: (24, 8, 18); 256 threads.
__global__ __launch_bounds__(256) void blockify_kernel(
    const float* __restrict__ x, const float* __restrict__ Wp,
    const float* __restrict__ Wo,
    ushort_t* __restrict__ xtb, ushort_t* __restrict__ WpTb,
    ushort_t* __restrict__ WoTb)
{
    const int zz = blockIdx.z;
    const float* in;
    ushort_t* out;
    int C, zbat;
    if (zz < 16)       { if (blockIdx.x >= 16) return; in = x;  out = xtb;  C = 1024; zbat = zz; }
    else if (zz == 16) {                               in = Wp; out = WpTb; C = 1536; zbat = 0;  }
    else               { if (blockIdx.x >= 8)  return; in = Wo; out = WoTb; C = 512;  zbat = 0;  }

    __shared__ float t[64][68];
    const int k0 = blockIdx.y * 64, c0 = blockIdx.x * 64;
    const float* inb = in + (size_t)zbat * 512 * C;
    const int tid = threadIdx.x;
#pragma unroll
    for (int i = 0; i < 4; ++i) {
        int idx = tid + i * 256;           // 0..1023 float4 slots
        int r = idx >> 4, c4 = idx & 15;
        float4 f = *(const float4*)&inb[(size_t)(k0 + r) * C + c0 + c4 * 4];
        *(float4*)&t[r][c4 * 4] = f;
    }
    __syncthreads();
    const size_t mbase = (size_t)zbat * C + c0;
    const int ml = tid & 63;
#pragma unroll
    for (int i = 0; i < 2; ++i) {
        int oct = (tid >> 6) + i * 4;          // k-octet 0..7
        size_t m = mbase + ml;
        int mt = (int)(m >> 7), mr = (int)(m & 127);
        int m16 = mr >> 4, col = mr & 15;
        int k = k0 + oct * 8;
        int it = k >> 5, q = (k >> 3) & 3;
        uint4 pk;
        pk.x = f2bf(t[oct * 8 + 0][ml]) | (f2bf(t[oct * 8 + 1][ml]) << 16);
        pk.y = f2bf(t[oct * 8 + 2][ml]) | (f2bf(t[oct * 8 + 3][ml]) << 16);
        pk.z = f2bf(t[oct * 8 + 4][ml]) | (f2bf(t[oct * 8 + 5][ml]) << 16);
        pk.w = f2bf(t[oct * 8 + 6][ml]) | (f2bf(t[oct * 8 + 7][ml]) << 16);
        size_t off = ((size_t)(mt * 16 + it) * 8 + m16) * 512 + (q * 16 + col) * 8;
        *(uint4*)&out[off] = pk;
    }
}

// ---------------------------------------------------------------------------
// Kernel 1: QKV GEMM (MFMA), BK=32, blocked contiguous staging, XCD swizzle.
//   v3: 4 waves x (64m x 64n), counted-vmcnt pipeline (T3+T4): prefetch
//   depth 2, raw barriers, vmcnt(4) keeps next tile's loads in flight.
//   v4: V written in pi-permuted row order so attn's PV A-fragments need
//   NO LDS round-trip.  Grid: (12, 128); 256 thr; 32 KB LDS.
// ---------------------------------------------------------------------------
__global__ __launch_bounds__(256) void qkv_gemm_kernel(
    const ushort_t* __restrict__ xtb, const ushort_t* __restrict__ WpTb,
    const float* __restrict__ bp,
    ushort_t* __restrict__ q_buf, ushort_t* __restrict__ kb,
    ushort_t* __restrict__ vb)
{
    __shared__ alignas(16) ushort_t Asub[2][8 * 512];   // 2 x 8 KB
    __shared__ alignas(16) ushort_t Bsub[2][8 * 512];   // 2 x 8 KB

    const int tid = threadIdx.x, w = tid >> 6, lane = tid & 63;
    const int quad = lane >> 4, col = lane & 15;
    const int wm = w >> 1, wn = w & 1;

    // XCD swizzle: all 12 n-tiles of one m-tile on one XCD
    const int lin = blockIdx.x + 12 * blockIdx.y;   // 0..1535
    const int xcd = lin & 7;
    const int rr  = lin >> 3;
    const int n0  = (rr % 12) * 128;
    const int m0  = ((rr / 12) * 8 + xcd) * 128;

    f32x4 acc[4][4];
#pragma unroll
    for (int i = 0; i < 4; ++i)
#pragma unroll
        for (int j = 0; j < 4; ++j) acc[i][j] = (f32x4){0.f, 0.f, 0.f, 0.f};

    const ushort_t* Ab = xtb  + (size_t)(m0 >> 7) * 65536 + (w * 2) * 512 + lane * 8;
    const ushort_t* Bb = WpTb + (size_t)(n0 >> 7) * 65536 + (w * 2) * 512 + lane * 8;

#define QKV_STAGE(buf, t)                                         \
    do {                                                          \
        async16(Ab + (t) * 4096,       &Asub[buf][(w * 2 + 0) * 512]); \
        async16(Ab + (t) * 4096 + 512, &Asub[buf][(w * 2 + 1) * 512]); \
        async16(Bb + (t) * 4096,       &Bsub[buf][(w * 2 + 0) * 512]); \
        async16(Bb + (t) * 4096 + 512, &Bsub[buf][(w * 2 + 1) * 512]); \
    } while (0)

    QKV_STAGE(0, 0);
    QKV_STAGE(1, 1);
    for (int it = 0; it < 16; ++it) {
        const int cur = it & 1;
        if (it < 15) { WAIT_VMCNT(4); } else { WAIT_VMCNT(0); }
        barrier_raw();                   // buf[cur] staged for all waves

        short8 af[4], bfr[4];
#pragma unroll
        for (int i = 0; i < 4; ++i) af[i]  = *(const short8*)&Asub[cur][(wm * 4 + i) * 512 + lane * 8];
#pragma unroll
        for (int j = 0; j < 4; ++j) bfr[j] = *(const short8*)&Bsub[cur][(wn * 4 + j) * 512 + lane * 8];
#pragma unroll
        for (int i = 0; i < 4; ++i)
#pragma unroll
            for (int j = 0; j < 4; ++j)
                acc[i][j] = __builtin_amdgcn_mfma_f32_16x16x32_bf16(af[i], bfr[j], acc[i][j], 0, 0, 0);

        if (it < 14) {
            barrier_raw();               // all waves done reading buf[cur]
            QKV_STAGE(cur, it + 2);
        }
    }
#undef QKV_STAGE

    // ---- epilogue: split q/k/v; q pre-scaled by QSCALE ----
    const int b = m0 >> 10, s0 = m0 & 1023;
    const size_t b8 = (size_t)b * HEADS;
#pragma unroll
    for (int j = 0; j < 4; ++j) {
        int nb = n0 + wn * 64 + j * 16;               // frag n base (wave-uniform)
        int h = nb / 192, rem = nb % 192;
        int type = rem >> 6, dbase = rem & 63;        // uniform per frag
        float bias = bp[nb + col];
        size_t bh = b8 + h;
        int d = dbase + col;
#pragma unroll
        for (int i = 0; i < 4; ++i) {
            int sb = s0 + wm * 64 + i * 16 + quad * 4;    // s for r=0
            f32x4 v = acc[i][j];
            if (type == 2) {
                // vb blocked + pi-permuted rows: slot tau for t=sb..sb+3 is
                // contiguous: tau&7 = ((sb>>4)&1)*4 + r, quad-slot = (sb>>2)&3
                unsigned lo = f2bf(v[0] + bias) | (f2bf(v[1] + bias) << 16);
                unsigned hi = f2bf(v[2] + bias) | (f2bf(v[3] + bias) << 16);
                uint2 pk; pk.x = lo; pk.y = hi;
                int itv = sb >> 6, sub = (d >> 4) * 2 + ((sb >> 5) & 1);
                size_t off = ((bh * 16 + itv) * 8 + sub) * 512
                           + (((sb >> 2) & 3) * 16 + (d & 15)) * 8
                           + ((sb >> 4) & 1) * 4;
                *(uint2*)&vb[off] = pk;
            } else if (type == 1) {
                // kb blocked: elem (bh,t,d): it=t>>6, sub=((t>>4)&3)*2+(d>>5)
#pragma unroll
                for (int r = 0; r < 4; ++r) {
                    int t = sb + r;
                    int itk = t >> 6, sub = ((t >> 4) & 3) * 2 + (d >> 5);
                    size_t off = ((bh * 16 + itk) * 8 + sub) * 512
                               + (((d >> 3) & 3) * 16 + (t & 15)) * 8 + (d & 7);
                    kb[off] = (ushort_t)f2bf(v[r] + bias);
                }
            } else {
#pragma unroll
                for (int r = 0; r < 4; ++r)
                    q_buf[(bh * SEQ + sb + r) * DHEAD + d] =
                        (ushort_t)f2bf((v[r] + bias) * QSCALE);
            }
        }
    }
}

// ---------------------------------------------------------------------------
// Kernel 2: MFMA flash attention; unnormalized softmax via exp2 (q
//   pre-scaled by log2e); S^T trick.
//   v4: ZERO P round-trip — V rows pi-permuted in vb so each lane's S^T
//   values ARE its PV A-fragment after exp2+pack.
//   v7: V read DIRECTLY from global into regs (vb fragment chunks are 1 KB
//   contiguous per wave, XCD-L2-resident) — no V LDS staging: DS traffic
//   per wave-iter halves (K only), barrier vmcnt drain halves (4 async16),
//   LDS 32->16 KB.  vf issued right after barrier, BEFORE K-prefetch
//   async16s, so PV's compiler wait is vmcnt(4) and K stays in flight.
//   2 waves x 4 q-groups (proven geometry); __syncthreads dbuf.
//   Grid: (bh=128, qtile=8); 128 threads.
// ---------------------------------------------------------------------------
__global__ __launch_bounds__(128) void attn_kernel(
    const ushort_t* __restrict__ q_buf, const ushort_t* __restrict__ kb,
    const ushort_t* __restrict__ vb, ushort_t* __restrict__ resb)
{
    __shared__ alignas(16) ushort_t Kf[2][8 * 512];   // ping-pong, 16 KB

    const int tid  = threadIdx.x;
    const int w    = tid >> 6;            // 0..1
    const int lane = tid & 63;
    const int quad = lane >> 4;
    const int col  = lane & 15;

    const int bhid = blockIdx.x;          // 0..127
    const int b = bhid >> 3, h = bhid & 7;
    const int q0 = blockIdx.y * 128;
    const size_t bh = (size_t)b * HEADS + h;

    // Q B-frags for 4 groups (pre-scaled by QSCALE in qkv_gemm)
    // group g covers q rows q0 + w*64 + g*16 .. +15
    const ushort_t* qp = q_buf + ((bh * SEQ) + q0 + w * 64 + col) * DHEAD + quad * 8;
    short8 qf0[4], qf1[4];
#pragma unroll
    for (int g = 0; g < 4; ++g) {
        qf0[g] = *(const short8*)(qp + g * 16 * DHEAD);
        qf1[g] = *(const short8*)(qp + g * 16 * DHEAD + 32);
    }

    short8 ones;
#pragma unroll
    for (int i = 0; i < 8; ++i) ones[i] = (short)0x3F80;

    f32x4 O[4][4];
#pragma unroll
    for (int g = 0; g < 4; ++g)
#pragma unroll
        for (int i = 0; i < 4; ++i) O[g][i] = (f32x4){0.f, 0.f, 0.f, 0.f};
    f32x4 L[4];
#pragma unroll
    for (int g = 0; g < 4; ++g) L[g] = (f32x4){0.f, 0.f, 0.f, 0.f};

    // K blocked contiguous staging (wave w stages subs w*4+{0..3})
    const ushort_t* kaB = kb + (size_t)bh * 65536 + (w * 4) * 512 + lane * 8;
    // V fragment base: chunk (it, s) at vgB + it*4096 + s*512 (1 KB/wave contig)
    const ushort_t* vgB = vb + (size_t)bh * 65536 + lane * 8;

#define ATTN_STAGE(buf)                                            \
    do {                                                           \
        async16(kaB,        &Kf[buf][(w * 4 + 0) * 512]);          \
        async16(kaB + 512,  &Kf[buf][(w * 4 + 1) * 512]);          \
        async16(kaB + 1024, &Kf[buf][(w * 4 + 2) * 512]);          \
        async16(kaB + 1536, &Kf[buf][(w * 4 + 3) * 512]);          \
        kaB += 4096;                                               \
    } while (0)

    ATTN_STAGE(0);

    for (int it = 0; it < 16; ++it) {
        const int cur = it & 1;
        const ushort_t* kc = Kf[cur];
        __syncthreads();   // Kf[cur] staged; prior readers of Kf[cur^1] done

        // ---- V frags direct from global (L2), issued BEFORE K prefetch so
        //      their completion wait leaves the newer async16s in flight ----
        short8 vf[8];
#pragma unroll
        for (int i = 0; i < 8; ++i)
            vf[i] = *(const short8*)&vgB[(size_t)it * 4096 + i * 512];

        if (it < 15) ATTN_STAGE(cur ^ 1);

        // ---- K frags to regs once; shared by all 4 groups ----
        short8 kf[8];
#pragma unroll
        for (int t16 = 0; t16 < 4; ++t16) {
            kf[2 * t16 + 0] = *(const short8*)&kc[(t16 * 2 + 0) * 512 + lane * 8];
            kf[2 * t16 + 1] = *(const short8*)&kc[(t16 * 2 + 1) * 512 + lane * 8];
        }

        // ---- per group: S^T = K Q^T; P fragments built IN REGISTERS ----
        // lane holds S^T[t=t16*16+quad*4+r][q=col]; under vb's pi-permutation
        // pf[0] = bf16(exp2(S[0][0..3]), exp2(S[1][0..3])), pf[1] = t16 2,3.
        short8 pf[4][2];
#pragma unroll
        for (int g = 0; g < 4; ++g) {
            f32x4 S[4];
            __builtin_amdgcn_s_setprio(1);
#pragma unroll
            for (int t16 = 0; t16 < 4; ++t16) {
                f32x4 a = (f32x4){0.f, 0.f, 0.f, 0.f};
                a = __builtin_amdgcn_mfma_f32_16x16x32_bf16(kf[2 * t16 + 0], qf0[g], a, 0, 0, 0);
                a = __builtin_amdgcn_mfma_f32_16x16x32_bf16(kf[2 * t16 + 1], qf1[g], a, 0, 0, 0);
                S[t16] = a;
            }
            __builtin_amdgcn_s_setprio(0);
            union { uint4 u; short8 s; } p0, p1;
            p0.u.x = pack_bf16_trunc(fast_exp2(S[0][0]), fast_exp2(S[0][1]));
            p0.u.y = pack_bf16_trunc(fast_exp2(S[0][2]), fast_exp2(S[0][3]));
            p0.u.z = pack_bf16_trunc(fast_exp2(S[1][0]), fast_exp2(S[1][1]));
            p0.u.w = pack_bf16_trunc(fast_exp2(S[1][2]), fast_exp2(S[1][3]));
            p1.u.x = pack_bf16_trunc(fast_exp2(S[2][0]), fast_exp2(S[2][1]));
            p1.u.y = pack_bf16_trunc(fast_exp2(S[2][2]), fast_exp2(S[2][3]));
            p1.u.z = pack_bf16_trunc(fast_exp2(S[3][0]), fast_exp2(S[3][1]));
            p1.u.w = pack_bf16_trunc(fast_exp2(S[3][2]), fast_exp2(S[3][3]));
            pf[g][0] = p0.s;
            pf[g][1] = p1.s;
        }

        // ---- O += P V ; V frags in regs, shared by 4 groups ----
#pragma unroll
        for (int d16 = 0; d16 < 4; ++d16) {
            const short8 v0 = vf[d16 * 2 + 0];
            const short8 v1 = vf[d16 * 2 + 1];
            __builtin_amdgcn_s_setprio(1);
#pragma unroll
            for (int g = 0; g < 4; ++g) {
                O[g][d16] = __builtin_amdgcn_mfma_f32_16x16x32_bf16(pf[g][0], v0, O[g][d16], 0, 0, 0);
                O[g][d16] = __builtin_amdgcn_mfma_f32_16x16x32_bf16(pf[g][1], v1, O[g][d16], 0, 0, 0);
            }
            __builtin_amdgcn_s_setprio(0);
        }
#pragma unroll
        for (int g = 0; g < 4; ++g) {
            L[g] = __builtin_amdgcn_mfma_f32_16x16x32_bf16(pf[g][0], ones, L[g], 0, 0, 0);
            L[g] = __builtin_amdgcn_mfma_f32_16x16x32_bf16(pf[g][1], ones, L[g], 0, 0, 0);
        }
    }
#undef ATTN_STAGE

    // ---- epilogue: O / L -> resb in out_gemm's blocked order ----
    const int mt = b * 8 + (q0 >> 7);
#pragma unroll
    for (int g = 0; g < 4; ++g) {
        const int m16 = w * 4 + g;
#pragma unroll
        for (int r = 0; r < 4; ++r) {
            float inv = 1.f / L[g][r];
            const int mcol = quad * 4 + r;
#pragma unroll
            for (int d16 = 0; d16 < 4; ++d16) {
                int itk = h * 2 + (d16 >> 1);
                int kq = (d16 & 1) * 2 + (col >> 3);
                size_t off = ((size_t)(mt * 16 + itk) * 8 + m16) * 512
                           + (kq * 16 + mcol) * 8 + (col & 7);
                resb[off] = (ushort_t)f2bf(O[g][d16][r] * inv);
            }
        }
    }
}

// ---------------------------------------------------------------------------
// Kernel 3: out GEMM (MFMA), BK=32, blocked staging, XCD swizzle.
//   v5: 64m x 128n tiles — grid (4, 256) = 1024 blocks = 4 blocks/CU.
//   4 waves as 2m x 2n (wave 32m x 64n, acc[2][4]); 3 async16/wave/tile;
//   WAIT_VMCNT(3); LDS 24 KB.  Coalesced LDS-transpose epilogue.
// ---------------------------------------------------------------------------
__global__ __launch_bounds__(256) void out_gemm_kernel(
    const ushort_t* __restrict__ resb, const ushort_t* __restrict__ WoTb,
    const float* __restrict__ bo, const float* __restrict__ x,
    float* __restrict__ out)
{
    __shared__ alignas(16) ushort_t SMEM[(2 * 4 + 2 * 8) * 512];   // 24 KB
    ushort_t (*Asub)[4 * 512] = (ushort_t (*)[4 * 512])(SMEM);
    ushort_t (*Bsub)[8 * 512] = (ushort_t (*)[8 * 512])(SMEM + 2 * 4 * 512);
    float* tb = (float*)SMEM;            // epilogue overlay [32][68] fp32 (8.7 KB)

    const int tid = threadIdx.x, w = tid >> 6, lane = tid & 63;
    const int quad = lane >> 4, col = lane & 15;
    const int wm = w >> 1, wn = w & 1;

    const int lin = blockIdx.x + 4 * blockIdx.y;    // 0..1023
    const int xcd = lin & 7;
    const int rr  = lin >> 3;                       // 0..127
    const int n0  = (rr & 3) * 128;
    const int m0  = ((rr >> 2) * 8 + xcd) * 64;     // 64-row m-tiles

    f32x4 acc[2][4];
#pragma unroll
    for (int i = 0; i < 2; ++i)
#pragma unroll
        for (int j = 0; j < 4; ++j) acc[i][j] = (f32x4){0.f, 0.f, 0.f, 0.f};

    const int mt = m0 >> 7, mhalf = (m0 >> 6) & 1;
    const ushort_t* Ab = resb + (size_t)mt * 65536 + (size_t)(mhalf * 4 + w) * 512 + lane * 8;
    const ushort_t* Bb = WoTb + (size_t)(n0 >> 7) * 65536 + (w * 2) * 512 + lane * 8;

#define OUT_STAGE(buf, t)                                              \
    do {                                                               \
        async16(Ab + (t) * 4096,       &Asub[buf][w * 512]);           \
        async16(Bb + (t) * 4096,       &Bsub[buf][(w * 2 + 0) * 512]); \
        async16(Bb + (t) * 4096 + 512, &Bsub[buf][(w * 2 + 1) * 512]); \
    } while (0)

    OUT_STAGE(0, 0);
    OUT_STAGE(1, 1);
    for (int it = 0; it < 16; ++it) {
        const int cur = it & 1;
        if (it < 15) { WAIT_VMCNT(3); } else { WAIT_VMCNT(0); }
        barrier_raw();

        short8 af[2], bfr[4];
#pragma unroll
        for (int i = 0; i < 2; ++i) af[i]  = *(const short8*)&Asub[cur][(wm * 2 + i) * 512 + lane * 8];
#pragma unroll
        for (int j = 0; j < 4; ++j) bfr[j] = *(const short8*)&Bsub[cur][(wn * 4 + j) * 512 + lane * 8];
#pragma unroll
        for (int i = 0; i < 2; ++i)
#pragma unroll
            for (int j = 0; j < 4; ++j)
                acc[i][j] = __builtin_amdgcn_mfma_f32_16x16x32_bf16(af[i], bfr[j], acc[i][j], 0, 0, 0);

        if (it < 14) {
            barrier_raw();
            OUT_STAGE(cur, it + 2);
        }
    }
#undef OUT_STAGE

    // ---- coalesced epilogue via LDS transpose ----
    // Per j-pass: waves stage acc[:,j] (32 n x 64 s fp32) into tb, then each
    // instruction streams 4 n-rows x 64 contiguous s (4 x 256 B segments).
    const int b = m0 >> 10, s0 = m0 & 1023;
#pragma unroll
    for (int j = 0; j < 4; ++j) {
        __syncthreads();   // previous pass readers / main-loop readers done
#pragma unroll
        for (int i = 0; i < 2; ++i) {
            f32x4 v = acc[i][j];
            float* dst = &tb[(wn * 16 + col) * 68 + wm * 32 + i * 16 + quad * 4];
            dst[0] = v[0]; dst[1] = v[1]; dst[2] = v[2]; dst[3] = v[3];
        }
        __syncthreads();   // tb fully staged
#pragma unroll
        for (int p = 0; p < 2; ++p) {
            int nl = w * 8 + p * 4 + (lane >> 4);          // 0..31
            int n = n0 + j * 16 + (nl & 15) + (nl >> 4) * 64;
            int scol = (lane & 15) * 4;
            float4 t4 = *(const float4*)&tb[nl * 68 + scol];
            size_t o = ((size_t)b * CDIM + n) * SEQ + s0 + scol;
            float4 xr = *(const float4*)&x[o];
            float bias = bo[n];
            float4 ov;
            ov.x = t4.x + bias + xr.x;
            ov.y = t4.y + bias + xr.y;
            ov.z = t4.z + bias + xr.z;
            ov.w = t4.w + bias + xr.w;
            *(float4*)&out[o] = ov;
        }
    }
}

// ---------------------------------------------------------------------------
extern "C" void kernel_launch(void* const* d_in, const int* in_sizes, int n_in,
                              void* d_out, int out_size, void* d_ws, size_t ws_size,
                              hipStream_t stream) {
    const float* x  = (const float*)d_in[0];   // (16, 512, 32, 32) fp32
    const float* Wp = (const float*)d_in[1];   // (512, 1536) fp32
    const float* bp = (const float*)d_in[2];   // (1536,) fp32
    const float* Wo = (const float*)d_in[3];   // (512, 512) fp32
    const float* bo = (const float*)d_in[4];   // (512,) fp32
    float* out = (float*)d_out;                // (16, 512, 32, 32) fp32

    // ws layout (ushort units), ~86 MB
    ushort_t* xtb   = (ushort_t*)d_ws;               // blocked [mt][it][sub][lane][8]
    ushort_t* WpTb  = xtb   + (size_t)8388608;
    ushort_t* WoTb  = WpTb  + (size_t)786432;
    ushort_t* q_buf = WoTb  + (size_t)262144;        // row-major [bh][s][d]
    ushort_t* kb    = q_buf + (size_t)8388608;       // attn-blocked
    ushort_t* vb    = kb    + (size_t)8388608;       // attn-blocked, pi-permuted rows
    ushort_t* resb  = vb    + (size_t)8388608;       // out_gemm-blocked

    blockify_kernel<<<dim3(24, 8, 18), 256, 0, stream>>>(x, Wp, Wo, xtb, WpTb, WoTb);
    qkv_gemm_kernel<<<dim3(12, 128), 256, 0, stream>>>(xtb, WpTb, bp, q_buf, kb, vb);
    attn_kernel<<<dim3(128, 8), 128, 0, stream>>>(q_buf, kb, vb, resb);
    out_gemm_kernel<<<dim3(4, 256), 256, 0, stream>>>(resb, WoTb, bo, x, out);
}